// Round 2
// baseline (459.284 us; speedup 1.0000x reference)
//
#include <hip/hip_runtime.h>

// EvoBinarizedLayer: out[p,b,o] = x@W0 + (1-x)@W1  =  x@(W0-W1) + colsum_i(W1)
// x:[32,512,1024] {0,1} fp32; w:[2,32,1024,1024] {0,1} fp32; out fp32. Exact in bf16.
// HBM-bound: ~400MB min traffic -> ~64us floor @6.3TB/s.
//
// R2: 256-thread blocks, 128x128 tile (m97 regime). R1 failed at 443us: 1024-thr
// block forced a 128-VGPR cap (4 waves/SIMD) vs ~160 live regs -> K-loop scratch
// spills; and 1 block/CU left every barrier vmcnt(0) drain exposed.
// Now: launch_bounds(256,3) -> cap 170, ~160 live, 3 blocks/CU overlap.

namespace {

constexpr int PP = 32;
constexpr int BB = 512;
constexpr int II = 1024;
constexpr int OO = 1024;

constexpr int BM = 128;   // b tile
constexpr int BN = 128;   // o tile
constexpr int BK = 32;    // k tile

constexpr int KPA = 40;   // A LDS row stride, bf16 elems (80B, 16B-aligned)

// B LDS: [o][k] bf16 with 16B pad per 4 rows; 16B-aligned b128 frag reads,
// transpose writes spread ~4-way in banks (free-ish per m136).
__device__ __forceinline__ int boff(int o, int k) {
    return o * 40 + (o >> 2) * 8 + k;
}

typedef __attribute__((ext_vector_type(8))) short bf16x8;
typedef __attribute__((ext_vector_type(4))) float f32x4;

constexpr int A_BYTES = BM * KPA * 2;                  // 10240
constexpr int B_BYTES = (BN * 40 + (BN / 4) * 8) * 2;  // 10752
constexpr int SMEM_BYTES = A_BYTES + B_BYTES;          // 20992 -> LDS not limiting

// fp32 -> bf16 truncation: exact for {0,+-1}. Pack two (lo,hi) into u32.
__device__ __forceinline__ unsigned pk2(float lo, float hi) {
    return (__float_as_uint(lo) >> 16) | (__float_as_uint(hi) & 0xFFFF0000u);
}

__global__ __launch_bounds__(256, 3) void ebl_kernel(const float* __restrict__ x,
                                                     const float* __restrict__ w,
                                                     float* __restrict__ out) {
    __shared__ __align__(16) char smem[SMEM_BYTES];
    unsigned short* As = (unsigned short*)smem;             // [128][KPA] bf16 [b][k]
    unsigned short* Bs = (unsigned short*)(smem + A_BYTES); // boff layout [o][k]
    float* Scr    = (float*)smem;           // post-loop: 8 groups x 128 o = 4KB
    float* ColSum = (float*)(smem + 4096);  // 128 floats

    const int t  = (int)threadIdx.x;
    const int l  = t & 63;
    const int wv = t >> 6;     // 0..3
    const int wm = wv & 1;     // wave m (b)
    const int wn = wv >> 1;    // wave n (o)
    const int lq = l >> 4;     // quad
    const int ln = l & 15;

    const int p  = (int)blockIdx.z;
    const int b0 = (int)blockIdx.y * BM;
    const int o0 = (int)blockIdx.x * BN;

    const float* xp  = x + ((size_t)p * BB + b0) * II;
    const float* w0p = w + (size_t)p * II * OO + o0;
    const float* w1p = w + (size_t)(PP + p) * II * OO + o0;

    // A staging: rows ar+{0,32,64,96}, 4 floats at col ac (8 lanes span a 32-f row).
    const int ar = t >> 3;        // 0..31
    const int ac = (t & 7) * 4;   // 0..28
    // B staging: k rows {k0,k0+1,k0+16,k0+17} x 4 o-cols at bc, both W0 and W1.
    const int kp = t >> 5;        // 0..7
    const int bc = (t & 31) * 4;  // 0..124
    const int k0 = 2 * kp;        // 0..14

    // K-loop-invariant fragment read offsets.
    int a_rd[4], b_rd[4];
#pragma unroll
    for (int mt = 0; mt < 4; ++mt)
        a_rd[mt] = (wm * 64 + mt * 16 + ln) * KPA + lq * 8;
#pragma unroll
    for (int nt = 0; nt < 4; ++nt)
        b_rd[nt] = boff(wn * 64 + nt * 16 + ln, lq * 8);

    f32x4 acc[4][4];
#pragma unroll
    for (int mt = 0; mt < 4; ++mt)
#pragma unroll
        for (int nt = 0; nt < 4; ++nt)
            acc[mt][nt] = (f32x4){0.f, 0.f, 0.f, 0.f};

    f32x4 csum = (f32x4){0.f, 0.f, 0.f, 0.f};  // colsum(W1) partial, o = bc..bc+3

    const float* xa  = xp + (size_t)ar * II + ac;
    const float* wa0 = w0p + (size_t)k0 * OO + bc;
    const float* wa1 = w1p + (size_t)k0 * OO + bc;

    for (int kk = 0; kk < II; kk += BK) {
        // ---- global loads (dwordx4, coalesced); issued before barrier so the
        // drain overlaps other resident blocks' compute ----
        f32x4 a0 = *(const f32x4*)(xa + kk);
        f32x4 a1 = *(const f32x4*)(xa + 32 * II + kk);
        f32x4 a2 = *(const f32x4*)(xa + 64 * II + kk);
        f32x4 a3 = *(const f32x4*)(xa + 96 * II + kk);
        const float* w0k = wa0 + (size_t)kk * OO;
        const float* w1k = wa1 + (size_t)kk * OO;
        f32x4 p00 = *(const f32x4*)(w0k);
        f32x4 p01 = *(const f32x4*)(w0k + OO);
        f32x4 p02 = *(const f32x4*)(w0k + 16 * OO);
        f32x4 p03 = *(const f32x4*)(w0k + 17 * OO);
        f32x4 p10 = *(const f32x4*)(w1k);
        f32x4 p11 = *(const f32x4*)(w1k + OO);
        f32x4 p12 = *(const f32x4*)(w1k + 16 * OO);
        f32x4 p13 = *(const f32x4*)(w1k + 17 * OO);

        __syncthreads();  // prev iteration's LDS frag reads complete

        // ---- A: bf16 truncate, k-contiguous b64 writes ----
        *(uint2*)(&As[ar * KPA + ac]) =
            make_uint2(pk2(a0.x, a0.y), pk2(a0.z, a0.w));
        *(uint2*)(&As[(ar + 32) * KPA + ac]) =
            make_uint2(pk2(a1.x, a1.y), pk2(a1.z, a1.w));
        *(uint2*)(&As[(ar + 64) * KPA + ac]) =
            make_uint2(pk2(a2.x, a2.y), pk2(a2.z, a2.w));
        *(uint2*)(&As[(ar + 96) * KPA + ac]) =
            make_uint2(pk2(a3.x, a3.y), pk2(a3.z, a3.w));

        // ---- B: diff in {-1,0,1}, colsum(W1), register transpose ----
        f32x4 d0 = p00 - p10;
        f32x4 d1 = p01 - p11;
        f32x4 d2 = p02 - p12;
        f32x4 d3 = p03 - p13;
        csum += p10; csum += p11; csum += p12; csum += p13;
#pragma unroll
        for (int c = 0; c < 4; ++c) {
            *(unsigned*)(&Bs[boff(bc + c, k0)])      = pk2(d0[c], d1[c]);
            *(unsigned*)(&Bs[boff(bc + c, k0 + 16)]) = pk2(d2[c], d3[c]);
        }

        __syncthreads();

        // ---- MFMA: wave tile 64x64, one K=32 step ----
        bf16x8 af[4], bfm[4];
#pragma unroll
        for (int mt = 0; mt < 4; ++mt)
            af[mt] = *(const bf16x8*)(&As[a_rd[mt]]);
#pragma unroll
        for (int nt = 0; nt < 4; ++nt)
            bfm[nt] = *(const bf16x8*)(&Bs[b_rd[nt]]);
#pragma unroll
        for (int mt = 0; mt < 4; ++mt)
#pragma unroll
            for (int nt = 0; nt < 4; ++nt)
                acc[mt][nt] = __builtin_amdgcn_mfma_f32_16x16x32_bf16(
                    af[mt], bfm[nt], acc[mt][nt], 0, 0, 0);
    }

    // ---- colsum(W1): 8 k-group partials -> 128 column sums (reuse A LDS) ----
    __syncthreads();
    *(f32x4*)(&Scr[kp * 128 + bc]) = csum;
    __syncthreads();
    if (t < 128) {
        float s = 0.f;
#pragma unroll
        for (int g = 0; g < 8; ++g) s += Scr[g * 128 + t];
        ColSum[t] = s;
    }
    __syncthreads();

    // ---- epilogue: C/D layout col=lane&15, row=quad*4+reg (m89/m91) ----
    float* op = out + (size_t)p * BB * OO + o0;
#pragma unroll
    for (int nt = 0; nt < 4; ++nt) {
        const int ocol = wn * 64 + nt * 16 + ln;
        const float cs = ColSum[ocol];
#pragma unroll
        for (int mt = 0; mt < 4; ++mt) {
            const int row = b0 + wm * 64 + mt * 16 + lq * 4;
#pragma unroll
            for (int r = 0; r < 4; ++r)
                op[(size_t)(row + r) * OO + ocol] = acc[mt][nt][r] + cs;
        }
    }
}

}  // namespace

extern "C" void kernel_launch(void* const* d_in, const int* in_sizes, int n_in,
                              void* d_out, int out_size, void* d_ws, size_t ws_size,
                              hipStream_t stream) {
    const float* x = (const float*)d_in[0];
    const float* w = (const float*)d_in[1];
    float* out = (float*)d_out;
    // x-fastest order: the 4 b-blocks sharing a w o-slice are 8 apart -> same XCD L2.
    dim3 grid(OO / BN, BB / BM, PP);  // (8, 4, 32) = 1024 blocks, ~3/CU resident
    ebl_kernel<<<grid, dim3(256, 1, 1), 0, stream>>>(x, w, out);
}